// Round 12
// baseline (189.352 us; speedup 1.0000x reference)
//
#include <hip/hip_runtime.h>
#include <hip/hip_bf16.h>
#include <string.h>

#define NB   2
#define SEQ  2048
#define EMB  1024
#define NH   16
#define HD   64
// softmax uses exp2: fold SCALE*log2(e) into Q pre-scale
#define QSCALE 0.045084219f       // (1/32) * log2(e)

typedef __attribute__((ext_vector_type(8))) short short8;   // 8 x bf16
typedef __attribute__((ext_vector_type(4))) float f32x4;    // MFMA C/D

#define MFMA(a, b, c) __builtin_amdgcn_mfma_f32_16x16x32_bf16(a, b, c, 0, 0, 0)
#define EXP2(x) __builtin_amdgcn_exp2f(x)

__device__ __forceinline__ unsigned short f2bf(float x) {
    union { float f; unsigned u; } v; v.f = x;
    unsigned r = v.u + 0x7fffu + ((v.u >> 16) & 1u);   // RNE
    return (unsigned short)(r >> 16);
}
__device__ __forceinline__ unsigned packbf2(float a, float b) {
    __hip_bfloat162 h = __float22bfloat162_rn(make_float2(a, b));  // hw v_cvt_pk
    unsigned u; memcpy(&u, &h, 4);
    return u;
}
// async global->LDS, 16B per lane; LDS dest = uniform base + lane*16 (linear)
__device__ __forceinline__ void gload16(const void* g, void* l) {
    __builtin_amdgcn_global_load_lds(
        (const __attribute__((address_space(1))) void*)g,
        (__attribute__((address_space(3))) void*)l, 16, 0, 0);
}

// ---------------------------------------------------------------------------
// Kernel 0: convert Wo/Wq/Wk/Wv fp32->bf16, build bf16 mask vector (1.0/0.0).
// (r11's fusion of this into qkv was net-negative — reverted to r10 form.)
// ---------------------------------------------------------------------------
__global__ __launch_bounds__(256) void cvt_kernel(
    const float* __restrict__ Wo, const float* __restrict__ Wq,
    const float* __restrict__ Wk, const float* __restrict__ Wv,
    const int* __restrict__ mask,
    unsigned short* __restrict__ Wob, unsigned short* __restrict__ Wqb,
    unsigned short* __restrict__ Wkb, unsigned short* __restrict__ Wvb,
    unsigned short* __restrict__ Mb)
{
    const int b = blockIdx.x, tid = threadIdx.x;
    if (b < 1024) {                       // Wo: 262144 float4
        int idx = b * 256 + tid;
        float4 w = ((const float4*)Wo)[idx];
        uint2 p; p.x = packbf2(w.x, w.y); p.y = packbf2(w.z, w.w);
        ((uint2*)Wob)[idx] = p;
    } else if (b < 1027) {                // Wq/Wk/Wv: 1024 float4 each
        const float* W = (b == 1024) ? Wq : (b == 1025) ? Wk : Wv;
        unsigned short* Wb = (b == 1024) ? Wqb : (b == 1025) ? Wkb : Wvb;
        #pragma unroll
        for (int i = 0; i < 4; ++i) {
            int idx = tid + i * 256;
            float4 w = ((const float4*)W)[idx];
            uint2 p; p.x = packbf2(w.x, w.y); p.y = packbf2(w.z, w.w);
            ((uint2*)Wb)[idx] = p;
        }
    } else {                              // Mb: NB*SEQ bf16 entries (1.0 / 0.0)
        #pragma unroll
        for (int i = 0; i < 16; ++i) {
            int idx = tid + i * 256;
            Mb[idx] = mask[idx] ? (unsigned short)0x3F80 : (unsigned short)0;
        }
    }
}

// ---------------------------------------------------------------------------
// Kernel 1: per-head QKV projection (r9/r10 proven version).
// grid (SEQ/128, NH, 3*NB), block 256.
// Q,K out: [n][h][l][d] bf16 (Q pre-scaled by QSCALE).  V out: [n][h][d][l],
// with MASKED ROWS OF V ZEROED.
// ---------------------------------------------------------------------------
__global__ __launch_bounds__(256) void qkv_kernel(
    const float* __restrict__ Qin, const float* __restrict__ Kin,
    const float* __restrict__ Vin,
    const unsigned short* __restrict__ Wqb, const unsigned short* __restrict__ Wkb,
    const unsigned short* __restrict__ Wvb, const float* __restrict__ bq,
    const int* __restrict__ mask,
    unsigned short* __restrict__ Qp, unsigned short* __restrict__ Kp,
    unsigned short* __restrict__ Vtp)
{
    const int lt = blockIdx.x;          // 128-row l tile
    const int h  = blockIdx.y;
    const int tz = blockIdx.z;
    const int t  = tz >> 1, n = tz & 1;

    const float* X; const unsigned short* Wb;
    if (t == 0)      { X = Qin; Wb = Wqb; }
    else if (t == 1) { X = Kin; Wb = Wkb; }
    else             { X = Vin; Wb = Wvb; }

    __shared__ __align__(16) unsigned short sX[128][70];
    __shared__ __align__(16) unsigned short sT[64][136];

    const int tid = threadIdx.x, wave = tid >> 6, lane = tid & 63;
    const int ln = lane & 15, quad = lane >> 4;

    #pragma unroll
    for (int i = 0; i < 8; ++i) {
        int flat = tid + i * 256;
        int r = flat >> 4, c4 = flat & 15;
        float4 xv = *(const float4*)(X + ((size_t)(n * SEQ + lt * 128 + r)) * EMB + h * HD + c4 * 4);
        uint2 xp; xp.x = packbf2(xv.x, xv.y); xp.y = packbf2(xv.z, xv.w);
        *(uint2*)&sX[r][c4 * 4] = xp;
    }
    short8 wf0[4], wf1[4];
    #pragma unroll
    for (int nt = 0; nt < 4; ++nt) {
        wf0[nt] = *(const short8*)(Wb + (nt * 16 + ln) * HD + quad * 8);
        wf1[nt] = *(const short8*)(Wb + (nt * 16 + ln) * HD + 32 + quad * 8);
    }
    __syncthreads();

    f32x4 acc[2][4];
    #pragma unroll
    for (int set = 0; set < 2; ++set) {
        short8 af0 = *(const short8*)&sX[wave * 32 + set * 16 + ln][quad * 8];
        short8 af1 = *(const short8*)&sX[wave * 32 + set * 16 + ln][32 + quad * 8];
        #pragma unroll
        for (int nt = 0; nt < 4; ++nt) {
            f32x4 a = {0.f, 0.f, 0.f, 0.f};
            a = MFMA(af0, wf0[nt], a);
            a = MFMA(af1, wf1[nt], a);
            acc[set][nt] = a;
        }
    }

    if (t == 0) {   // bias then fold softmax scale (incl. log2e)
        #pragma unroll
        for (int nt = 0; nt < 4; ++nt) {
            float bb = bq[nt * 16 + ln];
            #pragma unroll
            for (int set = 0; set < 2; ++set)
                #pragma unroll
                for (int a = 0; a < 4; ++a)
                    acc[set][nt][a] = (acc[set][nt][a] + bb) * QSCALE;
        }
    }

    if (t < 2) {
        unsigned short* Out = (t == 0) ? Qp : Kp;
        #pragma unroll
        for (int set = 0; set < 2; ++set)
            #pragma unroll
            for (int a = 0; a < 4; ++a) {
                size_t row = (size_t)((n * NH + h) * SEQ + lt * 128 + wave * 32 + set * 16 + quad * 4 + a);
                #pragma unroll
                for (int nt = 0; nt < 4; ++nt)
                    Out[row * HD + nt * 16 + ln] = f2bf(acc[set][nt][a]);
            }
    } else {
        // zero masked V rows (l = column of V^T)
        #pragma unroll
        for (int set = 0; set < 2; ++set)
            #pragma unroll
            for (int a = 0; a < 4; ++a) {
                int l = lt * 128 + wave * 32 + set * 16 + quad * 4 + a;
                if (mask[n * SEQ + l] == 0) {
                    #pragma unroll
                    for (int nt = 0; nt < 4; ++nt) acc[set][nt][a] = 0.f;
                }
            }
        #pragma unroll
        for (int set = 0; set < 2; ++set)
            #pragma unroll
            for (int nt = 0; nt < 4; ++nt)
                #pragma unroll
                for (int a = 0; a < 4; ++a)
                    sT[nt * 16 + ln][wave * 32 + set * 16 + quad * 4 + a] = f2bf(acc[set][nt][a]);
        __syncthreads();
        #pragma unroll
        for (int i = 0; i < 4; ++i) {
            int flat = tid + i * 256;
            int r = flat >> 4, c8 = flat & 15;
            *(float4*)(Vtp + ((size_t)((n * NH + h) * HD + r)) * SEQ + lt * 128 + c8 * 8) =
                *(const float4*)&sT[r][c8 * 8];
        }
    }
}

// ---------------------------------------------------------------------------
// Kernel 2: flash attention v14 — deferred-PV software pipeline.
// v12/v13 (55.6us): no pipe >55%; stall = per-kt serial chain
//   K-read -> QK-MFMA -> exp2 -> pack -> ds_write -> lgkmcnt(0) -> P-read -> PV
// with the asm lgkmcnt acting as a compiler barrier, at 2 waves/SIMD.
// v14: PV runs ONE ITERATION BEHIND QK.  Iteration i:
//   STAGE(i+1) async | PV(i-1) [sP slot (i-1)&1 + V-frags in REGISTERS
//   (vfA/vfB, loaded last iteration)] | QK(i) -> sP slot i&1 | VFLOAD(i) |
//   one barrier.  The barrier's implicit lgkmcnt(0) replaces the asm --
//   write->read distance is a full iteration, and PV's pure-MFMA stream and
//   QK's exp2/pack stream are independent, so the compiler interleaves them.
// LDS: Kb[2] 16K + Vb[2] 16K + sP[2 slots][4 waves] 32K = 64KB (2 blocks/CU,
// same as the 512-block grid gives).  No inline asm left.
// grid (NB*NH, SEQ/128), block 256 (4 waves x 32 q-rows).
// ---------------------------------------------------------------------------
__global__ __launch_bounds__(256, 2) void flash_kernel(
    const unsigned short* __restrict__ Qp, const unsigned short* __restrict__ Kp,
    const unsigned short* __restrict__ Vtp, const unsigned short* __restrict__ Mb,
    unsigned short* __restrict__ A /* [n][l][EMB] bf16 */)
{
    const int nh = blockIdx.x;
    const int qt = blockIdx.y;            // 128-row q tile
    const int n  = nh >> 4, h = nh & 15;

    const int tid  = threadIdx.x;
    const int wave = tid >> 6, lane = tid & 63;
    const int ln   = lane & 15, quad = lane >> 4;
    const int ln7  = lane & 7;

    __shared__ __align__(16) unsigned short Kb[2][64 * 64];       // 16 KiB
    __shared__ __align__(16) unsigned short Vb[2][64 * 64];       // 16 KiB
    __shared__ __align__(16) unsigned short sP[2][4][32 * 64];    // 32 KiB
    unsigned short* const sPw0 = &sP[0][wave][0];
    unsigned short* const sPw1 = &sP[1][wave][0];

    // Q B-fragments: wave owns q rows qt*128 + wave*32 + set*16 + ln
    const unsigned short* Qb = Qp + ((size_t)nh * SEQ + qt * 128 + wave * 32) * HD;
    short8 qf[2][2];
    #pragma unroll
    for (int set = 0; set < 2; ++set) {
        qf[set][0] = *(const short8*)(Qb + (set * 16 + ln) * HD + quad * 8);
        qf[set][1] = *(const short8*)(Qb + (set * 16 + ln) * HD + 32 + quad * 8);
    }

    const unsigned short* Kg = Kp  + (size_t)nh * SEQ * HD;
    const unsigned short* Vg = Vtp + (size_t)nh * HD * SEQ;
    const unsigned short* mk = Mb + n * SEQ;

    // loop-invariant swizzled LDS offsets (shorts)
    const int kx0 = ((quad)     ^ ln7) << 3;          // frag col, first half
    const int kx1 = ((quad + 4) ^ ln7) << 3;          // frag col, second half
    const int pw0 = ((quad >> 1) ^ ln7) << 3;         // sP write-chunk base (nt=0)
    const int pwb = (quad & 1) * 4;

    // staging geometry: each gload16 = 1 KiB = 8 rows of 128B.  Wave w stages
    // rows [16w, 16w+16) of both K and V.  Source chunk pre-swizzled so that
    // LDS(row, c) holds global(row, c ^ (row&7)).
    const int r8  = lane >> 3;                       // 0..7
    const int swz = ((lane & 7) ^ r8) << 3;          // shorts within row

    f32x4 o[2][4];
    #pragma unroll
    for (int s2 = 0; s2 < 2; ++s2)
        #pragma unroll
        for (int dt = 0; dt < 4; ++dt) o[s2][dt] = (f32x4){0.f, 0.f, 0.f, 0.f};
    f32x4 ol[2] = {(f32x4){0.f, 0.f, 0.f, 0.f}, (f32x4){0.f, 0.f, 0.f, 0.f}};

    short8 vfA[4][2], vfB[4][2];      // V fragments, double-set (rule #20: static names)

    #define STAGE(buf, kt_) do {                                                  \
        const unsigned short* kg_ = Kg + ((size_t)((kt_) * 64 + wave * 16 + r8)) * HD + swz; \
        const unsigned short* vg_ = Vg + ((size_t)(wave * 16 + r8)) * SEQ + (kt_) * 64 + swz; \
        unsigned short* kl_ = &Kb[buf][wave * 16 * 64];                           \
        unsigned short* vl_ = &Vb[buf][wave * 16 * 64];                           \
        gload16(kg_,            kl_);                                             \
        gload16(kg_ + 8 * HD,   kl_ + 8 * 64);                                    \
        gload16(vg_,            vl_);                                             \
        gload16(vg_ + 8 * SEQ,  vl_ + 8 * 64);                                    \
    } while (0)

    // QK(i): S^T = K Q^T, exp2, P -> sP[SPW] (swizzled).  All LDS offsets
    // static (buffer index is a literal).
    #define QK(SPW, KBUF, KT) do {                                               \
        _Pragma("unroll")                                                         \
        for (int nt = 0; nt < 4; ++nt) {                                          \
            short8 kf0 = *(const short8*)&Kb[KBUF][(nt * 16 + ln) * 64 + kx0];    \
            short8 kf1 = *(const short8*)&Kb[KBUF][(nt * 16 + ln) * 64 + kx1];    \
            _Pragma("unroll")                                                     \
            for (int set = 0; set < 2; ++set) {                                   \
                f32x4 z = {0.f, 0.f, 0.f, 0.f};                                   \
                z = MFMA(kf0, qf[set][0], z);                                     \
                z = MFMA(kf1, qf[set][1], z);                                     \
                float p0 = EXP2(z[0]);                                            \
                float p1 = EXP2(z[1]);                                            \
                float p2 = EXP2(z[2]);                                            \
                float p3 = EXP2(z[3]);                                            \
                uint2 w; w.x = packbf2(p0, p1); w.y = packbf2(p2, p3);            \
                *(uint2*)&(SPW)[(set * 16 + ln) * 64 + (pw0 ^ (nt * 2 << 3)) + pwb] = w; \
            }                                                                     \
        }                                                                         \
    } while (0)

    // VFLOAD(i): V fragments of tile i (buffer VBUF) -> registers for next iter
    #define VFLOAD(VF, VBUF) do {                                                 \
        _Pragma("unroll")                                                         \
        for (int dt = 0; dt < 4; ++dt) {                                          \
            (VF)[dt][0] = *(const short8*)&Vb[VBUF][(dt * 16 + ln) * 64 + kx0];   \
            (VF)[dt][1] = *(const short8*)&Vb[VBUF][(dt * 16 + ln) * 64 + kx1];   \
        }                                                                         \
    } while (0)

    // PV(i-1): O += P V (V from regs), l += P m (mask-MFMA)
    #define PV(SPW, VF, KT) do {                                                  \
        short8 mf0 = *(const short8*)(mk + (KT) * 64 + quad * 8);                 \
        short8 mf1 = *(const short8*)(mk + (KT) * 64 + 32 + quad * 8);            \
        short8 pf[2][2];                                                          \
        _Pragma("unroll")                                                         \
        for (int set = 0; set < 2; ++set) {                                       \
            pf[set][0] = *(const short8*)&(SPW)[(set * 16 + ln) * 64 + kx0];      \
            pf[set][1] = *(const short8*)&(SPW)[(set * 16 + ln) * 64 + kx1];      \
        }                                                                         \
        _Pragma("unroll")                                                         \
        for (int set = 0; set < 2; ++set) {                                       \
            ol[set] = MFMA(pf[set][0], mf0, ol[set]);                             \
            ol[set] = MFMA(pf[set][1], mf1, ol[set]);                             \
        }                                                                         \
        _Pragma("unroll")                                                         \
        for (int dt = 0; dt < 4; ++dt) {                                          \
            _Pragma("unroll")                                                     \
            for (int set = 0; set < 2; ++set) {                                   \
                o[set][dt] = MFMA(pf[set][0], (VF)[dt][0], o[set][dt]);           \
                o[set][dt] = MFMA(pf[set][1], (VF)[dt][1], o[set][dt]);           \
            }                                                                     \
        }                                                                         \
    } while (0)

    // ---- prologue ----
    STAGE(0, 0);
    __syncthreads();                      // tile 0 staged
    STAGE(1, 1);                          // prefetch tile 1
    QK(sPw0, 0, 0);                       // P(0) -> slot 0
    VFLOAD(vfA, 0);                       // V(0) -> regs
    __syncthreads();                      // tile 1 staged; P(0)/vfA ready

    // ---- main loop: iterations i = 1..30, unrolled x2 (all indices literal) ----
    #pragma unroll 1
    for (int m = 0; m < 15; ++m) {
        const int i1 = 2 * m + 1;         // odd:  sP slot 1, K/V buf 1
        // i = i1
        STAGE(0, i1 + 1);                 // tile i1+1 (even) -> buf 0
        PV(sPw0, vfA, i1 - 1);            // finish tile i1-1 (even: slot 0, vfA)
        QK(sPw1, 1, i1);                  // P(i1) -> slot 1
        VFLOAD(vfB, 1);                   // V(i1) -> regs
        __syncthreads();
        // i = i1+1 (even)
        STAGE(1, i1 + 2);                 // tile i1+2 (odd) -> buf 1
        PV(sPw1, vfB, i1);                // finish tile i1 (odd: slot 1, vfB)
        QK(sPw0, 0, i1 + 1);              // P(i1+1) -> slot 0
        VFLOAD(vfA, 0);                   // V(i1+1) -> regs
        __syncthreads();
    }
    // ---- peeled i = 31 (odd; no further staging) ----
    PV(sPw0, vfA, 30);
    QK(sPw1, 1, 31);
    VFLOAD(vfB, 1);
    __syncthreads();
    // ---- final PV(31) ----
    PV(sPw1, vfB, 31);

    #undef STAGE
    #undef QK
    #undef VFLOAD
    #undef PV

    // ---- normalize own rows and write (ol[set][a] aligns with o[set][dt][a]) ----
    #pragma unroll
    for (int set = 0; set < 2; ++set)
        #pragma unroll
        for (int a = 0; a < 4; ++a) {
            float inv = 1.0f / ol[set][a];
            size_t row = (size_t)(n * SEQ + qt * 128 + wave * 32 + set * 16 + quad * 4 + a);
            #pragma unroll
            for (int dt = 0; dt < 4; ++dt)
                A[row * EMB + h * HD + dt * 16 + ln] = f2bf(o[set][dt][a] * inv);
        }
}

// ---------------------------------------------------------------------------
// Kernel 3: out = A @ Wo^T + bo, 128x128 tile, flash-style async pipeline
// (r10 proven version).  global_load_lds dbuf, one barrier per kc, XOR-chunk
// swizzle.  grid (EMB/128, NB*SEQ/128), block 256 (2x2 waves of 64x64).
// ---------------------------------------------------------------------------
__global__ __launch_bounds__(256) void outproj_kernel(
    const unsigned short* __restrict__ A, const unsigned short* __restrict__ Wob,
    const float* __restrict__ bo, float* __restrict__ Out)
{
    const int ct = blockIdx.x;   // 128-col tile
    const int rt = blockIdx.y;   // 128-row tile

    const int tid  = threadIdx.x;
    const int wave = tid >> 6, lane = tid & 63;
    const int ln   = lane & 15, quad = lane >> 4;
    const int ln7  = lane & 7;
    const int wm   = wave >> 1, wn = wave & 1;

    __shared__ __align__(16) unsigned short sA[2][128 * 64];   // 16 KiB each
    __shared__ __align__(16) unsigned short sB[2][128 * 64];

    const int r8  = lane >> 3;                       // 0..7
    const int swz = ((lane & 7) ^ r8) << 3;          // shorts within row

    f32x4 acc[4][4];
    #pragma unroll
    for (int i = 0; i < 4; ++i)
        #pragma unroll
        for (int j = 0; j < 4; ++j) acc[i][j] = (f32x4){0.f, 0.f, 0.f, 0.f};

    #define STAGE(buf, kc_) do {                                                  \
        _Pragma("unroll")                                                         \
        for (int sub = 0; sub < 4; ++sub) {                                       \
            int rloc = wave * 32 + sub * 8;                                       \
            gload16(A   + (size_t)(rt * 128 + rloc + r8) * EMB + (kc_) * 64 + swz,\
                    &sA[buf][rloc * 64]);                                         \
            gload16(Wob + (size_t)(ct * 128 + rloc + r8) * EMB + (kc_) * 64 + swz,\
                    &sB[buf][rloc * 64]);                                         \
        }                                                                         \
    } while (0)

    #define COMPUTE(BUF) do {                                                     \
        _Pragma("unroll")                                                         \
        for (int ks = 0; ks < 2; ++ks) {                                          \
            short8 af[4], bf[4];                                                  \
            _Pragma("unroll")                                                     \
            for (int i = 0; i < 4; ++i)                                           \
                af[i] = *(const short8*)&sA[BUF][(wm * 64 + i * 16 + ln) * 64     \
                                                + (((ks * 4 + quad) ^ ln7) << 3)];\
            _Pragma("unroll")                                                     \
            for (int j = 0; j < 4; ++j)                                           \
                bf[j] = *(const short8*)&sB[BUF][(wn * 64 + j * 16 + ln) * 64     \
                                                + (((ks * 4 + quad) ^ ln7) << 3)];\
            _Pragma("unroll")                                                     \
            for (int i = 0; i < 4; ++i)                                           \
                _Pragma("unroll")                                                 \
                for (int j = 0; j < 4; ++j)                                       \
                    acc[i][j] = MFMA(af[i], bf[j], acc[i][j]);                    \
        }                                                                         \
    } while (0)

    STAGE(0, 0);
    __syncthreads();                       // drains vmcnt -> tile 0 ready

    #pragma unroll 1
    for (int kc = 0; kc < EMB / 64; kc += 2) {
        STAGE(1, kc + 1);                  // async prefetch
        COMPUTE(0);
        __syncthreads();                   // prefetch landed, all buf0 reads done
        if (kc + 2 < EMB / 64) STAGE(0, kc + 2);
        COMPUTE(1);
        __syncthreads();
    }
    #undef STAGE
    #undef COMPUTE

    #pragma unroll
    for (int j = 0; j < 4; ++j) {
        int col = ct * 128 + wn * 64 + j * 16 + ln;
        float bb = bo[col];
        #pragma unroll
        for (int i = 0; i < 4; ++i)
            #pragma unroll
            for (int a = 0; a < 4; ++a) {
                size_t row = (size_t)(rt * 128 + wm * 64 + i * 16 + quad * 4 + a);
                Out[row * EMB + col] = acc[i][j][a] + bb;
            }
    }
}

// ---------------------------------------------------------------------------
extern "C" void kernel_launch(void* const* d_in, const int* in_sizes, int n_in,
                              void* d_out, int out_size, void* d_ws, size_t ws_size,
                              hipStream_t stream) {
    const float* values = (const float*)d_in[0];
    const float* key_   = (const float*)d_in[1];
    const float* query  = (const float*)d_in[2];
    const int*   mask   = (const int*)d_in[3];
    const float* Wv     = (const float*)d_in[4];
    const float* Wk     = (const float*)d_in[5];
    const float* Wq     = (const float*)d_in[6];
    const float* bq     = (const float*)d_in[7];
    const float* Wo     = (const float*)d_in[8];
    const float* bo     = (const float*)d_in[9];
    float* out = (float*)d_out;

    const size_t NHLD = (size_t)NB * NH * SEQ * HD;   // 4,194,304

    unsigned short* ws = (unsigned short*)d_ws;
    unsigned short* Qp    = ws;
    unsigned short* Kp    = ws + NHLD;
    unsigned short* Vtp   = ws + 2 * NHLD;
    unsigned short* Aattn = ws + 3 * NHLD;
    unsigned short* Wob   = ws + 4 * NHLD;                  // EMB*EMB
    unsigned short* Wqb   = Wob + (size_t)EMB * EMB;
    unsigned short* Wkb   = Wqb + HD * HD;
    unsigned short* Wvb   = Wkb + HD * HD;
    unsigned short* Mb    = Wvb + HD * HD;                  // NB*SEQ bf16 mask

    cvt_kernel<<<dim3(1028), 256, 0, stream>>>(
        Wo, Wq, Wk, Wv, mask, Wob, Wqb, Wkb, Wvb, Mb);
    qkv_kernel<<<dim3(SEQ / 128, NH, 3 * NB), 256, 0, stream>>>(
        query, key_, values, Wqb, Wkb, Wvb, bq, mask, Qp, Kp, Vtp);
    flash_kernel<<<dim3(NB * NH, SEQ / 128), 256, 0, stream>>>(
        Qp, Kp, Vtp, Mb, Aattn);
    outproj_kernel<<<dim3(EMB / 128, NB * SEQ / 128), 256, 0, stream>>>(
        Aattn, Wob, bo, out);
}